// Round 11
// baseline (1253.409 us; speedup 1.0000x reference)
//
#include <hip/hip_runtime.h>
#include <string.h>

#define HIDDEN 128
#define LEAKY 0.01f
#define SCAN_CHUNK 1024   // 256 threads * 4 elems
#define TILE 16384        // edges per histogram/scatter tile
#define BSH 6             // bucket shift -> 64 nodes per bucket
#define BNODES 64         // 1 << BSH

// ---------------- helpers ----------------------------------------------------
__device__ __forceinline__ unsigned int rne_bf16(float f) {
    unsigned int x = __float_as_uint(f);
    return (x + 0x7FFFu + ((x >> 16) & 1u)) >> 16;
}

// ---------------- K1: fused tile-histogram + scores/cvt ----------------------
// Blocks [0, n_tiles): per-tile LDS histogram of buckets (h>>6) -> no global
// atomic contention; result hist_g[bucket * n_tiles + tile]. These blocks are
// FIRST so they start immediately and finish under the scores BW usage
// (round-10 lesson: appending them serialized into a tail).
// Blocks [n_tiles, ...): scores s_i/s_j + bf16 copy, 2 nodes per wave via
// float4 (halves wave count, doubles bytes in flight vs round-10).
template<bool CVT>
__global__ void hist_scores_k(const float* __restrict__ x,
                              const float* __restrict__ w_i,
                              const float* __restrict__ w_j,
                              float* __restrict__ s_i,
                              float* __restrict__ s_j,
                              unsigned short* __restrict__ xb,
                              const int* __restrict__ h,
                              int* __restrict__ hist_g,
                              int n_nodes, int n_edges,
                              int n_tiles, int n_buckets) {
    extern __shared__ int lhist[];
    int tid = threadIdx.x;
    if ((int)blockIdx.x < n_tiles) {
        for (int v = tid; v < n_buckets; v += 256) lhist[v] = 0;
        __syncthreads();
        int tbeg = blockIdx.x * TILE;
        int tend = min(tbeg + TILE, n_edges);
        #pragma unroll 1
        for (int s = 0; s < TILE / 1024; ++s) {
            int i0 = tbeg + s * 1024 + tid * 4;
            if (i0 + 4 <= tend) {
                int4 hv = *reinterpret_cast<const int4*>(h + i0);
                atomicAdd(&lhist[hv.x >> BSH], 1);
                atomicAdd(&lhist[hv.y >> BSH], 1);
                atomicAdd(&lhist[hv.z >> BSH], 1);
                atomicAdd(&lhist[hv.w >> BSH], 1);
            } else {
                for (int i = i0; i < tend; ++i) atomicAdd(&lhist[h[i] >> BSH], 1);
            }
        }
        __syncthreads();
        for (int v = tid; v < n_buckets; v += 256)
            hist_g[v * n_tiles + blockIdx.x] = lhist[v];
    } else {
        int w = (blockIdx.x - n_tiles) * 4 + (tid >> 6);
        int lane = tid & 63;
        int sub = lane & 31;
        int node = 2 * w + (lane >> 5);
        if (node >= n_nodes) return;
        const float4* xr = reinterpret_cast<const float4*>(x + (size_t)node * HIDDEN);
        float4 xv = xr[sub];
        if (CVT) {
            uint2 pk;
            pk.x = rne_bf16(xv.x) | (rne_bf16(xv.y) << 16);
            pk.y = rne_bf16(xv.z) | (rne_bf16(xv.w) << 16);
            reinterpret_cast<uint2*>(xb + (size_t)node * HIDDEN)[sub] = pk;
        }
        float4 wi = reinterpret_cast<const float4*>(w_i)[sub];
        float4 wj = reinterpret_cast<const float4*>(w_j)[sub];
        float di = xv.x * wi.x + xv.y * wi.y + xv.z * wi.z + xv.w * wi.w;
        float dj = xv.x * wj.x + xv.y * wj.y + xv.z * wj.z + xv.w * wj.w;
        #pragma unroll
        for (int off = 16; off > 0; off >>= 1) {   // reduce within 32-lane half
            di += __shfl_xor(di, off, 64);
            dj += __shfl_xor(dj, off, 64);
        }
        if (sub == 0) { s_i[node] = di; s_j[node] = dj; }
    }
}

// ---------------- K2: exclusive scan over hist_g (in place) ------------------
// NOTE: no __restrict__ on counts/offsets — called with the SAME pointer
// (in-place scan; each element read into registers before being overwritten
// by its own thread, chunks are block-disjoint).
__global__ void scan1_k(const int* counts, int* offsets,
                        int* blockSums, int n) {
    __shared__ int lds[256];
    int tid = threadIdx.x;
    int base = blockIdx.x * SCAN_CHUNK + tid * 4;
    int v0 = (base + 0 < n) ? counts[base + 0] : 0;
    int v1 = (base + 1 < n) ? counts[base + 1] : 0;
    int v2 = (base + 2 < n) ? counts[base + 2] : 0;
    int v3 = (base + 3 < n) ? counts[base + 3] : 0;
    int tsum = v0 + v1 + v2 + v3;
    lds[tid] = tsum;
    __syncthreads();
    for (int off = 1; off < 256; off <<= 1) {
        int addend = (tid >= off) ? lds[tid - off] : 0;
        __syncthreads();
        if (tid >= off) lds[tid] += addend;
        __syncthreads();
    }
    int incl = lds[tid];
    int excl = incl - tsum;
    if (tid == 255) blockSums[blockIdx.x] = incl;
    int run = excl;
    if (base + 0 < n) { offsets[base + 0] = run; } run += v0;
    if (base + 1 < n) { offsets[base + 1] = run; } run += v1;
    if (base + 2 < n) { offsets[base + 2] = run; } run += v2;
    if (base + 3 < n) { offsets[base + 3] = run; }
}

__global__ void scan2_k(int* blockSums, int nblocks) {
    __shared__ int lds[256];
    int tid = threadIdx.x;
    int v = (tid < nblocks) ? blockSums[tid] : 0;
    lds[tid] = v;
    __syncthreads();
    for (int off = 1; off < 256; off <<= 1) {
        int addend = (tid >= off) ? lds[tid - off] : 0;
        __syncthreads();
        if (tid >= off) lds[tid] += addend;
        __syncthreads();
    }
    if (tid < nblocks) blockSums[tid] = lds[tid] - v;  // exclusive
}

__global__ void scan3_k(int* offsets, const int* __restrict__ blockSums, int n) {
    int base = blockIdx.x * SCAN_CHUNK + threadIdx.x * 4;
    int add = blockSums[blockIdx.x];
    if (base + 0 < n) offsets[base + 0] += add;
    if (base + 1 < n) offsets[base + 1] += add;
    if (base + 2 < n) offsets[base + 2] += add;
    if (base + 3 < n) offsets[base + 3] += add;
}

// ---------------- K3: bucket-binned scatter ----------------------------------
// Tile re-reads its 16384 edges; rank within (bucket, tile) via LDS cursor
// (initialized from the scanned hist -> globally unique positions; hist_g
// itself stays intact for K4). Entries of one (bucket,tile) land in a ~8-entry
// contiguous run -> lines fill while L2-resident -> writebacks ~amp-1.5
// instead of the 64B-per-store amplification (101MB) of the random scatter.
__global__ void binscatter_k(const float* __restrict__ s_i,
                             const float* __restrict__ s_j,
                             const int* __restrict__ h,
                             const int* __restrict__ t,
                             const int* __restrict__ hist_g,
                             uint2* __restrict__ te,
                             int n_edges, int n_tiles, int n_buckets) {
    extern __shared__ int cur[];
    int tid = threadIdx.x;
    for (int v = tid; v < n_buckets; v += 256)
        cur[v] = hist_g[v * n_tiles + blockIdx.x];
    __syncthreads();
    int tbeg = blockIdx.x * TILE;
    int tend = min(tbeg + TILE, n_edges);
    #pragma unroll 1
    for (int s = 0; s < TILE / 1024; ++s) {
        int i0 = tbeg + s * 1024 + tid * 4;
        if (i0 + 4 <= tend) {
            int4 hv = *reinterpret_cast<const int4*>(h + i0);
            int4 tv = *reinterpret_cast<const int4*>(t + i0);
            int hh[4] = {hv.x, hv.y, hv.z, hv.w};
            int tt[4] = {tv.x, tv.y, tv.z, tv.w};
            float ex[4];
            #pragma unroll
            for (int k = 0; k < 4; ++k) {
                float e = s_i[hh[k]] + s_j[tt[k]];
                e = e > 0.0f ? e : LEAKY * e;
                ex[k] = __expf(e);   // softmax shift-invariant; e is O(+-10)
            }
            #pragma unroll
            for (int k = 0; k < 4; ++k) {
                int pos = atomicAdd(&cur[hh[k] >> BSH], 1);   // LDS atomic
                uint2 en;
                en.x = (unsigned)tt[k] | ((unsigned)(hh[k] & (BNODES - 1)) << 17);
                en.y = __float_as_uint(ex[k]);
                te[pos] = en;
            }
        } else {
            for (int i = i0; i < tend; ++i) {
                int hh = h[i], tt2 = t[i];
                float e = s_i[hh] + s_j[tt2];
                e = e > 0.0f ? e : LEAKY * e;
                float ex1 = __expf(e);
                int pos = atomicAdd(&cur[hh >> BSH], 1);
                uint2 en;
                en.x = (unsigned)tt2 | ((unsigned)(hh & (BNODES - 1)) << 17);
                en.y = __float_as_uint(ex1);
                te[pos] = en;
            }
        }
    }
}

// ---------------- K4: per-bucket aggregation in LDS, fused softmax+ReLU ------
// One block per bucket (64 nodes, 33KB LDS fp32 accumulator, 4 blocks/CU).
// pass1: ssum[row] += ex (LDS atomics). pass2: wave-per-edge unroll-8 row
// gathers, LDS fp32 atomic accumulate. finalize: relu(acc * 1/ssum), fully
// coalesced 32KB store per block. No per-node offsets/counts needed.
template<bool BF16>
__global__ void __launch_bounds__(256, 4) bucket_agg_k(
        const unsigned short* __restrict__ xb,
        const float* __restrict__ xf,
        const int* __restrict__ hist_g,
        const uint2* __restrict__ te,
        float* __restrict__ out,
        int n_nodes, int n_edges, int n_tiles, int n_buckets) {
    __shared__ float acc[BNODES * HIDDEN];
    __shared__ float ssum[BNODES];
    int tid = threadIdx.x;
    int bkt = blockIdx.x;
    int beg = hist_g[bkt * n_tiles];
    int end = (bkt + 1 < n_buckets) ? hist_g[(bkt + 1) * n_tiles] : n_edges;
    for (int i = tid; i < BNODES * HIDDEN; i += 256) acc[i] = 0.0f;
    if (tid < BNODES) ssum[tid] = 0.0f;
    __syncthreads();
    for (int i = beg + tid; i < end; i += 256) {        // pass 1: segment sums
        uint2 en = te[i];
        atomicAdd(&ssum[en.x >> 17], __uint_as_float(en.y));
    }
    __syncthreads();
    int wave = tid >> 6, lane = tid & 63;
    for (int j = beg + wave * 8; j < end; j += 32) {    // pass 2: accumulate
        uint2 en[8];
        unsigned u[8];
        float2 vf[8];
        #pragma unroll
        for (int k = 0; k < 8; ++k) {
            int jc = (j + k < end) ? j + k : end - 1;   // clamp: dup loads cached
            en[k] = te[jc];
        }
        #pragma unroll
        for (int k = 0; k < 8; ++k) {
            int tt = en[k].x & 0x1FFFF;
            if (BF16)
                u[k] = *reinterpret_cast<const unsigned*>(
                    xb + (size_t)tt * HIDDEN + 2 * lane);
            else
                vf[k] = reinterpret_cast<const float2*>(
                    xf + (size_t)tt * HIDDEN)[lane];
        }
        #pragma unroll
        for (int k = 0; k < 8; ++k) {
            float a = __uint_as_float(en[k].y);
            a = (j + k < end) ? a : 0.0f;               // zero padding slots
            int row = en[k].x >> 17;
            float fx, fy;
            if (BF16) {
                fx = __uint_as_float(u[k] << 16);
                fy = __uint_as_float(u[k] & 0xFFFF0000u);
            } else { fx = vf[k].x; fy = vf[k].y; }
            atomicAdd(&acc[row * HIDDEN + 2 * lane],     a * fx);
            atomicAdd(&acc[row * HIDDEN + 2 * lane + 1], a * fy);
        }
    }
    __syncthreads();
    if (tid < BNODES) ssum[tid] = ssum[tid] > 0.0f ? 1.0f / ssum[tid] : 0.0f;
    __syncthreads();
    size_t obase = (size_t)bkt * BNODES * HIDDEN;
    for (int i = tid; i < BNODES * HIDDEN; i += 256) {  // finalize, coalesced
        int row = i >> 7;
        int node = (bkt << BSH) + row;
        if (node < n_nodes) {
            float v = acc[i] * ssum[row];
            v = v > 0.0f ? v : 0.0f;                    // fused ReLU
            __builtin_nontemporal_store(v, out + obase + i);
        }
    }
}

extern "C" void kernel_launch(void* const* d_in, const int* in_sizes, int n_in,
                              void* d_out, int out_size, void* d_ws, size_t ws_size,
                              hipStream_t stream) {
    const float* x   = (const float*)d_in[0];
    const float* w_i = (const float*)d_in[1];
    const float* w_j = (const float*)d_in[2];
    const int*   h   = (const int*)d_in[3];
    const int*   t   = (const int*)d_in[4];
    float* out = (float*)d_out;

    const int n_nodes   = in_sizes[0] / HIDDEN;
    const int n_edges   = in_sizes[3];
    const int n_tiles   = (n_edges + TILE - 1) / TILE;
    const int n_buckets = (n_nodes + BNODES - 1) / BNODES;
    const int scan_n    = n_buckets * n_tiles;
    const int nchunks   = (scan_n + SCAN_CHUNK - 1) / SCAN_CHUNK;  // <= 256

    // Workspace layout (8B-align te):
    char* p = (char*)d_ws;
    float* s_i = (float*)p;      p += (size_t)n_nodes * 4;
    float* s_j = (float*)p;      p += (size_t)n_nodes * 4;
    int* hist_g = (int*)p;       p += (size_t)scan_n * 4;
    int* blockSums = (int*)p;    p += 256 * 4;
    p = (char*)(((uintptr_t)p + 7) & ~(uintptr_t)7);
    uint2* te = (uint2*)p;       p += (size_t)n_edges * 8;
    unsigned short* xb = (unsigned short*)p;
    p += (size_t)n_nodes * HIDDEN * 2;
    const bool use_bf16 = ws_size >= (size_t)(p - (char*)d_ws);

    const int shmem = n_buckets * (int)sizeof(int);
    const int score_blocks = (((n_nodes + 1) / 2) + 3) / 4;  // 2 nodes/wave

    // K1: tile histograms (first) + scores/cvt (fills the GPU behind them).
    if (use_bf16)
        hist_scores_k<true><<<n_tiles + score_blocks, 256, shmem, stream>>>(
            x, w_i, w_j, s_i, s_j, xb, h, hist_g,
            n_nodes, n_edges, n_tiles, n_buckets);
    else
        hist_scores_k<false><<<n_tiles + score_blocks, 256, shmem, stream>>>(
            x, w_i, w_j, s_i, s_j, nullptr, h, hist_g,
            n_nodes, n_edges, n_tiles, n_buckets);

    // K2: exclusive scan of (bucket, tile) table, in place.
    scan1_k<<<nchunks, 256, 0, stream>>>(hist_g, hist_g, blockSums, scan_n);
    scan2_k<<<1, 256, 0, stream>>>(blockSums, nchunks);
    scan3_k<<<nchunks, 256, 0, stream>>>(hist_g, blockSums, scan_n);

    // K3: binned scatter (LDS cursors; hist_g preserved for K4).
    binscatter_k<<<n_tiles, 256, shmem, stream>>>(s_i, s_j, h, t, hist_g, te,
                                                  n_edges, n_tiles, n_buckets);

    // K4: per-bucket LDS aggregation + softmax + ReLU.
    if (use_bf16)
        bucket_agg_k<true><<<n_buckets, 256, 0, stream>>>(
            xb, x, hist_g, te, out, n_nodes, n_edges, n_tiles, n_buckets);
    else
        bucket_agg_k<false><<<n_buckets, 256, 0, stream>>>(
            nullptr, x, hist_g, te, out, n_nodes, n_edges, n_tiles, n_buckets);
}

// Round 12
// 159.190 us; speedup vs baseline: 7.8737x; 7.8737x over previous
//
#include <hip/hip_runtime.h>
#include <string.h>

#define HIDDEN 128
#define LEAKY 0.01f
#define SCAN_CHUNK 1024   // 256 threads * 4 elems
#define TILE 16384        // edges per histogram/scatter tile
#define BSH 6             // bucket shift -> 64 nodes per bucket
#define BNODES 64         // 1 << BSH

// ---------------- helpers ----------------------------------------------------
__device__ __forceinline__ unsigned int rne_bf16(float f) {
    unsigned int x = __float_as_uint(f);
    return (x + 0x7FFFu + ((x >> 16) & 1u)) >> 16;
}

// ---------------- K1: fused tile-histogram + scores/cvt ----------------------
// Blocks [0, n_tiles): per-tile LDS histogram of buckets (h>>6).
// Blocks [n_tiles, ...): scores s_i/s_j + bf16 copy, 2 nodes/wave via float4.
// (measured r11: whole front half K1+K2+K3 ~= 50us)
template<bool CVT>
__global__ void hist_scores_k(const float* __restrict__ x,
                              const float* __restrict__ w_i,
                              const float* __restrict__ w_j,
                              float* __restrict__ s_i,
                              float* __restrict__ s_j,
                              unsigned short* __restrict__ xb,
                              const int* __restrict__ h,
                              int* __restrict__ hist_g,
                              int n_nodes, int n_edges,
                              int n_tiles, int n_buckets) {
    extern __shared__ int lhist[];
    int tid = threadIdx.x;
    if ((int)blockIdx.x < n_tiles) {
        for (int v = tid; v < n_buckets; v += 256) lhist[v] = 0;
        __syncthreads();
        int tbeg = blockIdx.x * TILE;
        int tend = min(tbeg + TILE, n_edges);
        #pragma unroll 1
        for (int s = 0; s < TILE / 1024; ++s) {
            int i0 = tbeg + s * 1024 + tid * 4;
            if (i0 + 4 <= tend) {
                int4 hv = *reinterpret_cast<const int4*>(h + i0);
                atomicAdd(&lhist[hv.x >> BSH], 1);
                atomicAdd(&lhist[hv.y >> BSH], 1);
                atomicAdd(&lhist[hv.z >> BSH], 1);
                atomicAdd(&lhist[hv.w >> BSH], 1);
            } else {
                for (int i = i0; i < tend; ++i) atomicAdd(&lhist[h[i] >> BSH], 1);
            }
        }
        __syncthreads();
        for (int v = tid; v < n_buckets; v += 256)
            hist_g[v * n_tiles + blockIdx.x] = lhist[v];
    } else {
        int w = (blockIdx.x - n_tiles) * 4 + (tid >> 6);
        int lane = tid & 63;
        int sub = lane & 31;
        int node = 2 * w + (lane >> 5);
        if (node >= n_nodes) return;
        const float4* xr = reinterpret_cast<const float4*>(x + (size_t)node * HIDDEN);
        float4 xv = xr[sub];
        if (CVT) {
            uint2 pk;
            pk.x = rne_bf16(xv.x) | (rne_bf16(xv.y) << 16);
            pk.y = rne_bf16(xv.z) | (rne_bf16(xv.w) << 16);
            reinterpret_cast<uint2*>(xb + (size_t)node * HIDDEN)[sub] = pk;
        }
        float4 wi = reinterpret_cast<const float4*>(w_i)[sub];
        float4 wj = reinterpret_cast<const float4*>(w_j)[sub];
        float di = xv.x * wi.x + xv.y * wi.y + xv.z * wi.z + xv.w * wi.w;
        float dj = xv.x * wj.x + xv.y * wj.y + xv.z * wj.z + xv.w * wj.w;
        #pragma unroll
        for (int off = 16; off > 0; off >>= 1) {   // reduce within 32-lane half
            di += __shfl_xor(di, off, 64);
            dj += __shfl_xor(dj, off, 64);
        }
        if (sub == 0) { s_i[node] = di; s_j[node] = dj; }
    }
}

// ---------------- K2: exclusive scan over hist_g (in place) ------------------
__global__ void scan1_k(const int* counts, int* offsets,
                        int* blockSums, int n) {
    __shared__ int lds[256];
    int tid = threadIdx.x;
    int base = blockIdx.x * SCAN_CHUNK + tid * 4;
    int v0 = (base + 0 < n) ? counts[base + 0] : 0;
    int v1 = (base + 1 < n) ? counts[base + 1] : 0;
    int v2 = (base + 2 < n) ? counts[base + 2] : 0;
    int v3 = (base + 3 < n) ? counts[base + 3] : 0;
    int tsum = v0 + v1 + v2 + v3;
    lds[tid] = tsum;
    __syncthreads();
    for (int off = 1; off < 256; off <<= 1) {
        int addend = (tid >= off) ? lds[tid - off] : 0;
        __syncthreads();
        if (tid >= off) lds[tid] += addend;
        __syncthreads();
    }
    int incl = lds[tid];
    int excl = incl - tsum;
    if (tid == 255) blockSums[blockIdx.x] = incl;
    int run = excl;
    if (base + 0 < n) { offsets[base + 0] = run; } run += v0;
    if (base + 1 < n) { offsets[base + 1] = run; } run += v1;
    if (base + 2 < n) { offsets[base + 2] = run; } run += v2;
    if (base + 3 < n) { offsets[base + 3] = run; }
}

__global__ void scan2_k(int* blockSums, int nblocks) {
    __shared__ int lds[256];
    int tid = threadIdx.x;
    int v = (tid < nblocks) ? blockSums[tid] : 0;
    lds[tid] = v;
    __syncthreads();
    for (int off = 1; off < 256; off <<= 1) {
        int addend = (tid >= off) ? lds[tid - off] : 0;
        __syncthreads();
        if (tid >= off) lds[tid] += addend;
        __syncthreads();
    }
    if (tid < nblocks) blockSums[tid] = lds[tid] - v;  // exclusive
}

__global__ void scan3_k(int* offsets, const int* __restrict__ blockSums, int n) {
    int base = blockIdx.x * SCAN_CHUNK + threadIdx.x * 4;
    int add = blockSums[blockIdx.x];
    if (base + 0 < n) offsets[base + 0] += add;
    if (base + 1 < n) offsets[base + 1] += add;
    if (base + 2 < n) offsets[base + 2] += add;
    if (base + 3 < n) offsets[base + 3] += add;
}

// ---------------- K3: bucket-binned scatter (measured fast, r11) -------------
__global__ void binscatter_k(const float* __restrict__ s_i,
                             const float* __restrict__ s_j,
                             const int* __restrict__ h,
                             const int* __restrict__ t,
                             const int* __restrict__ hist_g,
                             uint2* __restrict__ te,
                             int n_edges, int n_tiles, int n_buckets) {
    extern __shared__ int cur[];
    int tid = threadIdx.x;
    for (int v = tid; v < n_buckets; v += 256)
        cur[v] = hist_g[v * n_tiles + blockIdx.x];
    __syncthreads();
    int tbeg = blockIdx.x * TILE;
    int tend = min(tbeg + TILE, n_edges);
    #pragma unroll 1
    for (int s = 0; s < TILE / 1024; ++s) {
        int i0 = tbeg + s * 1024 + tid * 4;
        if (i0 + 4 <= tend) {
            int4 hv = *reinterpret_cast<const int4*>(h + i0);
            int4 tv = *reinterpret_cast<const int4*>(t + i0);
            int hh[4] = {hv.x, hv.y, hv.z, hv.w};
            int tt[4] = {tv.x, tv.y, tv.z, tv.w};
            float ex[4];
            #pragma unroll
            for (int k = 0; k < 4; ++k) {
                float e = s_i[hh[k]] + s_j[tt[k]];
                e = e > 0.0f ? e : LEAKY * e;
                ex[k] = __expf(e);   // softmax shift-invariant; e is O(+-10)
            }
            #pragma unroll
            for (int k = 0; k < 4; ++k) {
                int pos = atomicAdd(&cur[hh[k] >> BSH], 1);   // LDS atomic
                uint2 en;
                en.x = (unsigned)tt[k] | ((unsigned)(hh[k] & (BNODES - 1)) << 17);
                en.y = __float_as_uint(ex[k]);
                te[pos] = en;
            }
        } else {
            for (int i = i0; i < tend; ++i) {
                int hh = h[i], tt2 = t[i];
                float e = s_i[hh] + s_j[tt2];
                e = e > 0.0f ? e : LEAKY * e;
                float ex1 = __expf(e);
                int pos = atomicAdd(&cur[hh >> BSH], 1);
                uint2 en;
                en.x = (unsigned)tt2 | ((unsigned)(hh & (BNODES - 1)) << 17);
                en.y = __float_as_uint(ex1);
                te[pos] = en;
            }
        }
    }
}

// ---------------- K4: per-bucket node-sort (te -> te2, node-contiguous) ------
// One block per bucket. Only 64 LDS counters. pass1: count rows; wave-scan ->
// per-node global offsets (monotone across the whole te2 permutation, so
// aggregate uses end = offsets[node+1]). pass2: re-scatter bucket entries
// (span ~8KB, L2-resident) to node order. NO wide LDS accumulators/atomics
// (r11 lesson: 205M LDS atomic RMWs = 1203us).
__global__ void bucket_sort_k(const uint2* __restrict__ te,
                              uint2* __restrict__ te2,
                              const int* __restrict__ hist_g,
                              int* __restrict__ offsets,
                              int n_nodes, int n_edges,
                              int n_tiles, int n_buckets) {
    __shared__ int cnt[BNODES];
    __shared__ int off[BNODES];
    int tid = threadIdx.x;
    int bkt = blockIdx.x;
    int beg = hist_g[bkt * n_tiles];
    int end = (bkt + 1 < n_buckets) ? hist_g[(bkt + 1) * n_tiles] : n_edges;
    if (tid < BNODES) cnt[tid] = 0;
    __syncthreads();
    for (int i = beg + tid; i < end; i += 256)
        atomicAdd(&cnt[te[i].x >> 17], 1);
    __syncthreads();
    if (tid < BNODES) {                 // exclusive scan of 64 counters (wave 0)
        int v = cnt[tid];
        int incl = v;
        #pragma unroll
        for (int o = 1; o < BNODES; o <<= 1) {
            int u = __shfl_up(incl, o, 64);
            if (tid >= o) incl += u;
        }
        int excl = incl - v;
        off[tid] = excl;
        int node = (bkt << BSH) + tid;
        if (node < n_nodes) offsets[node] = beg + excl;
        if (bkt == n_buckets - 1 && tid == 0) offsets[n_nodes] = n_edges;
        cnt[tid] = 0;
    }
    __syncthreads();
    for (int i = beg + tid; i < end; i += 256) {
        uint2 en = te[i];
        int row = en.x >> 17;
        int pos = beg + off[row] + atomicAdd(&cnt[row], 1);
        te2[pos] = en;
    }
}

// ---------------- K5: register aggregation, fused ReLU (proven r7 form) ------
// One wave per node; bf16 row gathers (256B). readfirstlane(node) -> wave-
// uniform metadata -> s_load. Main loop: unpredicated unroll-8; tail: ONE
// predicated 8-wide block.
__global__ void aggregate_bf16_k(const unsigned short* __restrict__ xb,
                                 const int* __restrict__ offsets,
                                 const long long* __restrict__ te2,
                                 float* __restrict__ out,
                                 int n_nodes) {
    int gtid = blockIdx.x * blockDim.x + threadIdx.x;
    int node = __builtin_amdgcn_readfirstlane(gtid >> 6);  // wave-uniform
    int lane = threadIdx.x & 63;
    if (node >= n_nodes) return;
    long long* dst = reinterpret_cast<long long*>(out + (size_t)node * HIDDEN) + lane;
    int beg = offsets[node];           // s_load
    int end = offsets[node + 1];       // s_load (monotone permutation)
    int deg = end - beg;
    if (deg <= 0) {                    // must still write out (harness poisons)
        __builtin_nontemporal_store(0LL, dst);
        return;
    }
    float accx = 0.0f, accy = 0.0f, ssum = 0.0f;
    int j = beg;
    int main_end = beg + (deg & ~7);
    for (; j < main_end; j += 8) {     // unpredicated main loop
        long long te[8];
        unsigned int u[8];
        #pragma unroll
        for (int k = 0; k < 8; ++k) te[k] = te2[j + k];
        #pragma unroll
        for (int k = 0; k < 8; ++k)
            u[k] = *reinterpret_cast<const unsigned int*>(
                xb + (size_t)((int)te[k] & 0x1FFFF) * HIDDEN + 2 * lane);
        #pragma unroll
        for (int k = 0; k < 8; ++k) {
            float a = __int_as_float((int)(te[k] >> 32));
            float fx = __uint_as_float(u[k] << 16);
            float fy = __uint_as_float(u[k] & 0xFFFF0000u);
            ssum += a;
            accx += a * fx;
            accy += a * fy;
        }
    }
    if (j < end) {                     // single predicated tail block
        long long te[8];
        unsigned int u[8];
        #pragma unroll
        for (int k = 0; k < 8; ++k) {
            int jj = j + k;
            int jc = jj < end ? jj : end - 1;   // clamp: dup loads hit cache
            te[k] = te2[jc];
        }
        #pragma unroll
        for (int k = 0; k < 8; ++k)
            u[k] = *reinterpret_cast<const unsigned int*>(
                xb + (size_t)((int)te[k] & 0x1FFFF) * HIDDEN + 2 * lane);
        #pragma unroll
        for (int k = 0; k < 8; ++k) {
            float a = __int_as_float((int)(te[k] >> 32));
            a = (j + k < end) ? a : 0.0f;       // zero padding slots
            float fx = __uint_as_float(u[k] << 16);
            float fy = __uint_as_float(u[k] & 0xFFFF0000u);
            ssum += a;
            accx += a * fx;
            accy += a * fy;
        }
    }
    float inv = 1.0f / ssum;
    float ox = accx * inv, oy = accy * inv;
    float2 o;
    o.x = ox > 0.0f ? ox : 0.0f;   // fused ReLU
    o.y = oy > 0.0f ? oy : 0.0f;
    long long bits;
    memcpy(&bits, &o, 8);
    __builtin_nontemporal_store(bits, dst);     // don't evict x from L2/L3
}

// fp32 fallback (only if ws can't hold the bf16 copy).
__global__ void aggregate_f32_k(const float* __restrict__ x,
                                const int* __restrict__ offsets,
                                const uint2* __restrict__ te2,
                                float* __restrict__ out,
                                int n_nodes) {
    int gtid = blockIdx.x * blockDim.x + threadIdx.x;
    int node = __builtin_amdgcn_readfirstlane(gtid >> 6);
    int lane = threadIdx.x & 63;
    if (node >= n_nodes) return;
    long long* dst = reinterpret_cast<long long*>(out + (size_t)node * HIDDEN) + lane;
    int beg = offsets[node];
    int end = offsets[node + 1];
    int deg = end - beg;
    if (deg <= 0) {
        __builtin_nontemporal_store(0LL, dst);
        return;
    }
    float accx = 0.0f, accy = 0.0f, ssum = 0.0f;
    for (int j = beg; j < end; j += 8) {
        uint2 te[8];
        float2 v[8];
        #pragma unroll
        for (int k = 0; k < 8; ++k) {
            int jj = j + k;
            int jc = jj < end ? jj : end - 1;
            te[k] = te2[jc];
        }
        #pragma unroll
        for (int k = 0; k < 8; ++k)
            v[k] = reinterpret_cast<const float2*>(
                x + (size_t)(te[k].x & 0x1FFFF) * HIDDEN)[lane];
        #pragma unroll
        for (int k = 0; k < 8; ++k) {
            float a = __uint_as_float(te[k].y);
            a = (j + k < end) ? a : 0.0f;
            ssum += a;
            accx += a * v[k].x;
            accy += a * v[k].y;
        }
    }
    float inv = 1.0f / ssum;
    float ox = accx * inv, oy = accy * inv;
    float2 o;
    o.x = ox > 0.0f ? ox : 0.0f;
    o.y = oy > 0.0f ? oy : 0.0f;
    long long bits;
    memcpy(&bits, &o, 8);
    __builtin_nontemporal_store(bits, dst);
}

extern "C" void kernel_launch(void* const* d_in, const int* in_sizes, int n_in,
                              void* d_out, int out_size, void* d_ws, size_t ws_size,
                              hipStream_t stream) {
    const float* x   = (const float*)d_in[0];
    const float* w_i = (const float*)d_in[1];
    const float* w_j = (const float*)d_in[2];
    const int*   h   = (const int*)d_in[3];
    const int*   t   = (const int*)d_in[4];
    float* out = (float*)d_out;

    const int n_nodes   = in_sizes[0] / HIDDEN;
    const int n_edges   = in_sizes[3];
    const int n_tiles   = (n_edges + TILE - 1) / TILE;
    const int n_buckets = (n_nodes + BNODES - 1) / BNODES;
    const int scan_n    = n_buckets * n_tiles;
    const int nchunks   = (scan_n + SCAN_CHUNK - 1) / SCAN_CHUNK;  // <= 256

    // Workspace layout (8B-align te):
    char* p = (char*)d_ws;
    float* s_i = (float*)p;      p += (size_t)n_nodes * 4;
    float* s_j = (float*)p;      p += (size_t)n_nodes * 4;
    int* hist_g = (int*)p;       p += (size_t)scan_n * 4;
    int* blockSums = (int*)p;    p += 256 * 4;
    int* offsets = (int*)p;      p += (size_t)(n_nodes + 1) * 4;
    p = (char*)(((uintptr_t)p + 7) & ~(uintptr_t)7);
    uint2* te = (uint2*)p;       p += (size_t)n_edges * 8;
    uint2* te2 = (uint2*)p;      p += (size_t)n_edges * 8;
    unsigned short* xb = (unsigned short*)p;
    p += (size_t)n_nodes * HIDDEN * 2;
    const bool use_bf16 = ws_size >= (size_t)(p - (char*)d_ws);

    const int shmem = n_buckets * (int)sizeof(int);
    const int score_blocks = (((n_nodes + 1) / 2) + 3) / 4;  // 2 nodes/wave

    // K1: tile histograms (first) + scores/cvt (fills the GPU behind them).
    if (use_bf16)
        hist_scores_k<true><<<n_tiles + score_blocks, 256, shmem, stream>>>(
            x, w_i, w_j, s_i, s_j, xb, h, hist_g,
            n_nodes, n_edges, n_tiles, n_buckets);
    else
        hist_scores_k<false><<<n_tiles + score_blocks, 256, shmem, stream>>>(
            x, w_i, w_j, s_i, s_j, nullptr, h, hist_g,
            n_nodes, n_edges, n_tiles, n_buckets);

    // K2: exclusive scan of (bucket, tile) table, in place.
    scan1_k<<<nchunks, 256, 0, stream>>>(hist_g, hist_g, blockSums, scan_n);
    scan2_k<<<1, 256, 0, stream>>>(blockSums, nchunks);
    scan3_k<<<nchunks, 256, 0, stream>>>(hist_g, blockSums, scan_n);

    // K3: binned scatter (LDS cursors; hist_g preserved).
    binscatter_k<<<n_tiles, 256, shmem, stream>>>(s_i, s_j, h, t, hist_g, te,
                                                  n_edges, n_tiles, n_buckets);

    // K4: per-bucket node-sort -> te2 + per-node offsets.
    bucket_sort_k<<<n_buckets, 256, 0, stream>>>(te, te2, hist_g, offsets,
                                                 n_nodes, n_edges,
                                                 n_tiles, n_buckets);

    // K5: register aggregate + softmax + ReLU, wave per node.
    {
        int blocks = (n_nodes * 64 + 255) / 256;
        if (use_bf16)
            aggregate_bf16_k<<<blocks, 256, 0, stream>>>(
                xb, offsets, reinterpret_cast<const long long*>(te2),
                out, n_nodes);
        else
            aggregate_f32_k<<<blocks, 256, 0, stream>>>(
                x, offsets, te2, out, n_nodes);
    }
}